// Round 1
// baseline (1465.354 us; speedup 1.0000x reference)
//
#include <hip/hip_runtime.h>
#include <hip/hip_bf16.h>

// Problem constants (match reference)
#define BB 4
#define NN 50000
#define EE 160000
#define KK 1000
#define CH 128
#define TM 64                          // nodes per GEMM tile
#define NTILES ((NN + TM - 1) / TM)    // 782

// ---------------------------------------------------------------------------
// Layer-0 aggregation: agg0[b][dst] += x[b][src]  (scalar per node)
// ---------------------------------------------------------------------------
__global__ __launch_bounds__(256)
void agg0_kernel(const float* __restrict__ x, const int* __restrict__ edges,
                 float* __restrict__ agg0) {
  int stride = gridDim.x * blockDim.x;
  for (int i = blockIdx.x * blockDim.x + threadIdx.x; i < BB * EE; i += stride) {
    int b = i / EE, e = i - b * EE;
    int src = edges[(b * 2) * EE + e];
    int dst = edges[(b * 2 + 1) * EE + e];
    atomicAdd(&agg0[b * NN + dst], x[b * NN + src]);
  }
}

// ---------------------------------------------------------------------------
// Layers 1..2 aggregation: agg[b][dst][c] += h[b][src][c]
// 128 consecutive threads handle the 128 channels of one edge (coalesced).
// ---------------------------------------------------------------------------
__global__ __launch_bounds__(256)
void agg_kernel(const float* __restrict__ h, const int* __restrict__ edges,
                float* __restrict__ agg) {
  const int total = BB * EE * CH;  // 81,920,000 < 2^31
  int stride = gridDim.x * blockDim.x;
  for (int i = blockIdx.x * blockDim.x + threadIdx.x; i < total; i += stride) {
    int c = i & (CH - 1);
    int t = i >> 7;
    int b = t / EE, e = t - b * EE;
    int src = edges[(b * 2) * EE + e];
    int dst = edges[(b * 2 + 1) * EE + e];
    atomicAdd(&agg[(b * NN + dst) * CH + c], h[(b * NN + src) * CH + c]);
  }
}

// ---------------------------------------------------------------------------
// Fused GIN layer GEMM:  hout = relu( relu((h+agg) @ w1 + b1) @ w2 + b2 )
// Tile: 64 nodes x 128 outputs per 256-thread block.
// Thread (tm4 = tid>>4, tj = tid&15) owns a 4-node x 8-col register tile.
// zt[c][m] (pad 68 floats -> 272B rows, 16B aligned, conflict-free b128 reads)
// wb stages 32 weight rows at a time (4 quarters) -> LDS stays under 64KB.
// ---------------------------------------------------------------------------
__device__ __forceinline__ void mm_quarter(const float (*zt)[TM + 4],
                                           const float (*wb)[CH + 4],
                                           int q, int tm4, int tj,
                                           float acc[4][8]) {
#pragma unroll 4
  for (int r = 0; r < 32; ++r) {
    int c = q * 32 + r;
    const float4 zv = *(const float4*)&zt[c][tm4 * 4];
    const float4 wa = *(const float4*)&wb[r][tj * 8];
    const float4 wc = *(const float4*)&wb[r][tj * 8 + 4];
    const float za[4] = {zv.x, zv.y, zv.z, zv.w};
    const float wv[8] = {wa.x, wa.y, wa.z, wa.w, wc.x, wc.y, wc.z, wc.w};
#pragma unroll
    for (int i = 0; i < 4; ++i)
#pragma unroll
      for (int k = 0; k < 8; ++k)
        acc[i][k] = fmaf(za[i], wv[k], acc[i][k]);
  }
}

template <bool L0>
__global__ __launch_bounds__(256, 2)
void gemm_kernel(const float* __restrict__ hin,   // L0: x (B*N), else h (B*N*C, relu'd)
                 const float* __restrict__ aggp,  // L0: agg0 (B*N), else agg (B*N*C)
                 float* __restrict__ hout,        // B*N*C (may alias hin)
                 const float* __restrict__ w1,    // L0: 128 ; else 128x128
                 const float* __restrict__ w2,    // 128x128
                 const float* __restrict__ b1v,   // 128
                 const float* __restrict__ b2v) { // 128
  __shared__ float zt[CH][TM + 4];   // 34,816 B
  __shared__ float wb[32][CH + 4];   // 16,896 B
  __shared__ float sz0[TM];

  const int tid = threadIdx.x;
  const int tj = tid & 15;
  const int tm4 = tid >> 4;

  const int tile = blockIdx.x;
  const int b = tile / NTILES;
  const int t0 = (tile - b * NTILES) * TM;
  const int nm = min(TM, NN - t0);
  const int base = b * NN + t0;

  float acc[4][8];

  if (L0) {
    // t[m][c] = relu(z0[m]*w1f[c] + b1[c]) written transposed into zt
    if (tid < TM) {
      float v = 0.f;
      if (tid < nm) v = hin[base + tid] + aggp[base + tid];
      sz0[tid] = v;
    }
    __syncthreads();
    for (int i = tid; i < TM * CH; i += 256) {
      int m = i >> 7, c = i & 127;
      zt[c][m] = fmaxf(sz0[m] * w1[c] + b1v[c], 0.f);
    }
    __syncthreads();
  } else {
    // stage z = h + agg, transposed
    for (int i = tid; i < TM * CH; i += 256) {
      int m = i >> 7, c = i & 127;
      float v = 0.f;
      if (m < nm) {
        int idx = (base + m) * CH + c;
        v = hin[idx] + aggp[idx];
      }
      zt[c][m] = v;
    }
    __syncthreads();

    // GEMM1: t = relu(z @ w1 + b1)
#pragma unroll
    for (int i = 0; i < 4; ++i)
#pragma unroll
      for (int k = 0; k < 8; ++k) acc[i][k] = 0.f;

    for (int q = 0; q < 4; ++q) {
      for (int i = tid; i < 32 * CH; i += 256) {
        int r = i >> 7, c2 = i & 127;
        wb[r][c2] = w1[(q * 32 + r) * CH + c2];
      }
      __syncthreads();
      mm_quarter(zt, wb, q, tm4, tj, acc);
      __syncthreads();
    }

    // bias + relu, then write t transposed back into zt
#pragma unroll
    for (int i = 0; i < 4; ++i)
#pragma unroll
      for (int k = 0; k < 8; ++k)
        acc[i][k] = fmaxf(acc[i][k] + b1v[tj * 8 + k], 0.f);
#pragma unroll
    for (int k = 0; k < 8; ++k) {
      float4 v = make_float4(acc[0][k], acc[1][k], acc[2][k], acc[3][k]);
      *(float4*)&zt[tj * 8 + k][tm4 * 4] = v;
    }
    __syncthreads();
  }

  // GEMM2: out = relu(t @ w2 + b2)
#pragma unroll
  for (int i = 0; i < 4; ++i)
#pragma unroll
    for (int k = 0; k < 8; ++k) acc[i][k] = 0.f;

  for (int q = 0; q < 4; ++q) {
    for (int i = tid; i < 32 * CH; i += 256) {
      int r = i >> 7, c2 = i & 127;
      wb[r][c2] = w2[(q * 32 + r) * CH + c2];
    }
    __syncthreads();
    mm_quarter(zt, wb, q, tm4, tj, acc);
    __syncthreads();
  }

#pragma unroll
  for (int i = 0; i < 4; ++i) {
    int m = tm4 * 4 + i;
    if (m < nm) {
      float o[8];
#pragma unroll
      for (int k = 0; k < 8; ++k)
        o[k] = fmaxf(acc[i][k] + b2v[tj * 8 + k], 0.f);
      float* dst = &hout[(base + m) * CH + tj * 8];
      *(float4*)dst = make_float4(o[0], o[1], o[2], o[3]);
      *(float4*)(dst + 4) = make_float4(o[4], o[5], o[6], o[7]);
    }
  }
}

// ---------------------------------------------------------------------------
// Heads: policy[b][k] = emb[b][didx[b][k]] . pol_w + pol_b
//        value[b]     = emb[b][didx[b][nop]] . val_w + val_b
// One wave per (b,k).
// ---------------------------------------------------------------------------
__global__ __launch_bounds__(256)
void heads_kernel(const float* __restrict__ emb, const int* __restrict__ didx,
                  const int* __restrict__ nopp,
                  const float* __restrict__ pol_w, const float* __restrict__ pol_b,
                  const float* __restrict__ val_w, const float* __restrict__ val_b,
                  float* __restrict__ out) {
  int gw = (blockIdx.x * blockDim.x + threadIdx.x) >> 6;
  int lane = threadIdx.x & 63;
  if (gw >= BB * KK) return;
  int b = gw / KK, k = gw - b * KK;
  int node = didx[b * KK + k];
  const float* e = emb + (size_t)(b * NN + node) * CH;

  float s = e[lane] * pol_w[lane] + e[lane + 64] * pol_w[lane + 64];
#pragma unroll
  for (int off = 32; off > 0; off >>= 1) s += __shfl_down(s, off);
  if (lane == 0) out[b * KK + k] = s + pol_b[0];

  if (k == nopp[0]) {
    float v = e[lane] * val_w[lane] + e[lane + 64] * val_w[lane + 64];
#pragma unroll
    for (int off = 32; off > 0; off >>= 1) v += __shfl_down(v, off);
    if (lane == 0) out[BB * KK + b] = v + val_b[0];
  }
}

// ---------------------------------------------------------------------------
extern "C" void kernel_launch(void* const* d_in, const int* in_sizes, int n_in,
                              void* d_out, int out_size, void* d_ws, size_t ws_size,
                              hipStream_t stream) {
  const float* x     = (const float*)d_in[0];
  const int*   edges = (const int*)d_in[1];
  const int*   didx  = (const int*)d_in[2];
  const int*   nopp  = (const int*)d_in[3];
  const float* w1f   = (const float*)d_in[4];
  const float* w1r   = (const float*)d_in[5];
  const float* w2    = (const float*)d_in[6];
  const float* b1    = (const float*)d_in[7];
  const float* b2    = (const float*)d_in[8];
  const float* pol_w = (const float*)d_in[9];
  const float* pol_b = (const float*)d_in[10];
  const float* val_w = (const float*)d_in[11];
  const float* val_b = (const float*)d_in[12];
  float* out = (float*)d_out;

  // workspace layout: h (B*N*C) | agg (B*N*C) | agg0 (B*N)  = ~205.6 MB
  float* h    = (float*)d_ws;
  float* agg  = h + (size_t)BB * NN * CH;
  float* agg0 = agg + (size_t)BB * NN * CH;

  const int tiles = BB * NTILES;

  // layer 0
  hipMemsetAsync(agg0, 0, (size_t)BB * NN * sizeof(float), stream);
  agg0_kernel<<<2500, 256, 0, stream>>>(x, edges, agg0);
  gemm_kernel<true><<<tiles, 256, 0, stream>>>(x, agg0, h, w1f, w2, b1, b2);

  // layers 1..2
  for (int l = 1; l < 3; ++l) {
    hipMemsetAsync(agg, 0, (size_t)BB * NN * CH * sizeof(float), stream);
    agg_kernel<<<8192, 256, 0, stream>>>(h, edges, agg);
    gemm_kernel<false><<<tiles, 256, 0, stream>>>(
        h, agg, h, w1r + (size_t)(l - 1) * CH * CH, w2 + (size_t)l * CH * CH,
        b1 + (size_t)l * CH, b2 + (size_t)l * CH);
  }

  heads_kernel<<<(BB * KK * 64 + 255) / 256, 256, 0, stream>>>(
      h, didx, nopp, pol_w, pol_b, val_w, val_b, out);
}

// Round 2
// 442.092 us; speedup vs baseline: 3.3146x; 3.3146x over previous
//
#include <hip/hip_runtime.h>
#include <hip/hip_bf16.h>

#define BB 4
#define NN 50000
#define EE 160000
#define KK 1000
#define CH 128
#define TM 64
#define NTILES ((NN + TM - 1) / TM)   // 782

typedef unsigned short u16;
typedef unsigned int u32;
typedef __attribute__((ext_vector_type(8))) short short8;
typedef __attribute__((ext_vector_type(4))) float f32x4;

// swizzled index into a [rows][128] u16 LDS tile: XOR bits 3..5 of k with row&7
// (byte_off ^= (row&7)<<4) -> conflict-free ds_read_b128 fragment loads (G4)
__device__ __forceinline__ int ZIDX(int m, int k) {
  return (m << 7) | (k ^ ((m & 7) << 3));
}

__device__ __forceinline__ u16 f2b(float f) {
  __hip_bfloat16 h = __float2bfloat16(f);   // RNE
  return *reinterpret_cast<u16*>(&h);
}
__device__ __forceinline__ float b2f(u32 lo16) {
  return __uint_as_float(lo16 << 16);
}

// ---------------------------------------------------------------------------
// CSR build
// ---------------------------------------------------------------------------
__global__ __launch_bounds__(256)
void csr_count(const int* __restrict__ edges, int* __restrict__ cnt) {
  int stride = gridDim.x * blockDim.x;
  for (int i = blockIdx.x * blockDim.x + threadIdx.x; i < BB * EE; i += stride) {
    int b = i / EE, e = i - b * EE;
    int dst = edges[(b * 2 + 1) * EE + e];
    atomicAdd(&cnt[b * NN + dst], 1);
  }
}

__global__ __launch_bounds__(256)
void csr_scan(const int* __restrict__ cnt, int* __restrict__ offs,
              int* __restrict__ woff) {
  __shared__ int sdata[256];
  const int g = blockIdx.x, t = threadIdx.x;
  const int chunk = (NN + 255) / 256;  // 196
  const int lo = t * chunk, hi = min(lo + chunk, NN);
  int s = 0;
  for (int i = lo; i < hi; ++i) s += cnt[g * NN + i];
  sdata[t] = s;
  __syncthreads();
  for (int off = 1; off < 256; off <<= 1) {
    int v = (t >= off) ? sdata[t - off] : 0;
    __syncthreads();
    sdata[t] += v;
    __syncthreads();
  }
  int run = sdata[t] - s;  // exclusive prefix
  for (int i = lo; i < hi; ++i) {
    offs[g * (NN + 1) + i] = run;
    woff[g * NN + i] = run;
    run += cnt[g * NN + i];
  }
  if (t == 255) offs[g * (NN + 1) + NN] = run;
}

__global__ __launch_bounds__(256)
void csr_fill(const int* __restrict__ edges, int* __restrict__ woff,
              int* __restrict__ csr_src) {
  int stride = gridDim.x * blockDim.x;
  for (int i = blockIdx.x * blockDim.x + threadIdx.x; i < BB * EE; i += stride) {
    int b = i / EE, e = i - b * EE;
    int src = edges[(b * 2) * EE + e];
    int dst = edges[(b * 2 + 1) * EE + e];
    int pos = atomicAdd(&woff[b * NN + dst], 1);
    csr_src[b * EE + pos] = src;
  }
}

// ---------------------------------------------------------------------------
// Weight prep: bf16, transposed (n-major), pre-swizzled LDS images.
// mats: 0:w2[0]  1:w1r[0]  2:w2[1]  3:w1r[1]  4:w2[2]
// ---------------------------------------------------------------------------
__global__ __launch_bounds__(256)
void prep_weights(const float* __restrict__ w1r, const float* __restrict__ w2,
                  u16* __restrict__ img) {
  int i = blockIdx.x * blockDim.x + threadIdx.x;
  if (i >= 5 * CH * CH) return;
  int mat = i >> 14, rem = i & 16383;
  int k = rem >> 7, n = rem & 127;
  const float* src;
  switch (mat) {
    case 0: src = w2; break;
    case 1: src = w1r; break;
    case 2: src = w2 + 16384; break;
    case 3: src = w1r + 16384; break;
    default: src = w2 + 32768; break;
  }
  img[(mat << 14) + ZIDX(n, k)] = f2b(src[(k << 7) + n]);
}

// ---------------------------------------------------------------------------
// Fused GIN layer: gather (CSR) + dual MFMA GEMM + relu, bf16 h in/out.
// Tile 64 nodes x 128 ch, 256 threads (4 waves). Wave w owns 32 out-cols.
// LDS: zt[64][128] bf16 (swz) + wt[128][128] bf16 (swz) = 48KB -> 3 blk/CU.
// ---------------------------------------------------------------------------
template <bool L0>
__global__ __launch_bounds__(256)
void gin_layer(const void* __restrict__ hin_v, u16* __restrict__ hout,
               const int* __restrict__ offs, const int* __restrict__ csr_src,
               const float* __restrict__ w1f,       // L0 only (128)
               const u16* __restrict__ img_w1,      // !L0
               const u16* __restrict__ img_w2,
               const float* __restrict__ b1v, const float* __restrict__ b2v) {
  __shared__ u16 zt[TM * CH];
  __shared__ u16 wt[CH * CH];
  __shared__ float part[L0 ? TM * 4 : 1];

  const int tid = threadIdx.x;
  const int lane = tid & 63;
  const int wv = tid >> 6;
  const int g = lane >> 4;    // k-group within frag
  const int lr = lane & 15;   // A-row / B-col within subtile
  const int cb = wv * 32;

  const int tile = blockIdx.x;
  const int b = tile / NTILES;
  const int t0 = (tile - b * NTILES) * TM;
  const int nm = min(TM, NN - t0);

  // stage first weight (w1 for !L0, w2 for L0) — images are pre-swizzled
  {
    const uint4* src = (const uint4*)(L0 ? img_w2 : img_w1);
    uint4* dst = (uint4*)wt;
    for (int i = tid; i < 2048; i += 256) dst[i] = src[i];
  }

  // ---- stage A-tile: z = h[dst] + sum_{src} h[src]  (4 threads/row, 32ch ea)
  const int m = tid >> 2;
  const int p = tid & 3;
  const int gnode = t0 + m;
  int start = 0, end = 0;
  if (m < nm) {
    start = offs[b * (NN + 1) + gnode];
    end = offs[b * (NN + 1) + gnode + 1];
  }

  if (L0) {
    const float* x = (const float*)hin_v;
    float s = 0.f;
    if (m < nm) {
      if (p == 0) s = x[b * NN + gnode];
      for (int e = start + p; e < end; e += 4) s += x[b * NN + csr_src[b * EE + e]];
    }
    part[(m << 2) + p] = s;
    __syncthreads();
    float z0 = part[m << 2] + part[(m << 2) + 1] + part[(m << 2) + 2] +
               part[(m << 2) + 3];
    for (int j = 0; j < 4; ++j) {
      int c0 = (p << 5) + (j << 3);
      short8 tv;
#pragma unroll
      for (int t = 0; t < 8; ++t)
        tv[t] = (short)f2b(fmaxf(z0 * w1f[c0 + t] + b1v[c0 + t], 0.f));
      *(short8*)&zt[ZIDX(m, c0)] = tv;
    }
    __syncthreads();
  } else {
    const u16* h = (const u16*)hin_v;
    float acc[32];
#pragma unroll
    for (int t = 0; t < 32; ++t) acc[t] = 0.f;
    if (m < nm) {
      {  // self
        const uint4* hr = (const uint4*)(h + ((size_t)(b * NN + gnode) << 7));
#pragma unroll
        for (int j = 0; j < 4; ++j) {
          uint4 v = hr[(p << 2) + j];
          acc[j*8+0] += b2f(v.x & 0xffff); acc[j*8+1] += b2f(v.x >> 16);
          acc[j*8+2] += b2f(v.y & 0xffff); acc[j*8+3] += b2f(v.y >> 16);
          acc[j*8+4] += b2f(v.z & 0xffff); acc[j*8+5] += b2f(v.z >> 16);
          acc[j*8+6] += b2f(v.w & 0xffff); acc[j*8+7] += b2f(v.w >> 16);
        }
      }
      for (int e = start; e < end; ++e) {
        int src = csr_src[b * EE + e];
        const uint4* hr = (const uint4*)(h + ((size_t)(b * NN + src) << 7));
#pragma unroll
        for (int j = 0; j < 4; ++j) {
          uint4 v = hr[(p << 2) + j];
          acc[j*8+0] += b2f(v.x & 0xffff); acc[j*8+1] += b2f(v.x >> 16);
          acc[j*8+2] += b2f(v.y & 0xffff); acc[j*8+3] += b2f(v.y >> 16);
          acc[j*8+4] += b2f(v.z & 0xffff); acc[j*8+5] += b2f(v.z >> 16);
          acc[j*8+6] += b2f(v.w & 0xffff); acc[j*8+7] += b2f(v.w >> 16);
        }
      }
    }
    for (int j = 0; j < 4; ++j) {
      int c0 = (p << 5) + (j << 3);
      short8 tv;
#pragma unroll
      for (int t = 0; t < 8; ++t) tv[t] = (short)f2b(acc[(j << 3) + t]);
      *(short8*)&zt[ZIDX(m, c0)] = tv;
    }
    __syncthreads();

    // ---- GEMM1: t = relu(z @ w1 + b1)
    f32x4 a1[4][2];
#pragma unroll
    for (int rt = 0; rt < 4; ++rt)
#pragma unroll
      for (int ct = 0; ct < 2; ++ct) a1[rt][ct] = (f32x4){0.f, 0.f, 0.f, 0.f};
#pragma unroll
    for (int k0 = 0; k0 < CH; k0 += 32) {
      int kb = k0 + (g << 3);
      short8 af[4], bfr[2];
#pragma unroll
      for (int rt = 0; rt < 4; ++rt)
        af[rt] = *(const short8*)&zt[ZIDX((rt << 4) + lr, kb)];
#pragma unroll
      for (int ct = 0; ct < 2; ++ct)
        bfr[ct] = *(const short8*)&wt[ZIDX(cb + (ct << 4) + lr, kb)];
#pragma unroll
      for (int rt = 0; rt < 4; ++rt)
#pragma unroll
        for (int ct = 0; ct < 2; ++ct)
          a1[rt][ct] = __builtin_amdgcn_mfma_f32_16x16x32_bf16(
              af[rt], bfr[ct], a1[rt][ct], 0, 0, 0);
    }
    __syncthreads();  // all zt/wt reads done

    // write t into zt (swizzled); stage w2 into wt
    {
      const uint4* src = (const uint4*)img_w2;
      uint4* dst = (uint4*)wt;
      for (int i = tid; i < 2048; i += 256) dst[i] = src[i];
    }
#pragma unroll
    for (int rt = 0; rt < 4; ++rt)
#pragma unroll
      for (int ct = 0; ct < 2; ++ct) {
        int col = cb + (ct << 4) + lr;
        float bias = b1v[col];
#pragma unroll
        for (int r = 0; r < 4; ++r) {
          int row = (rt << 4) + (g << 2) + r;
          zt[ZIDX(row, col)] = f2b(fmaxf(a1[rt][ct][r] + bias, 0.f));
        }
      }
    __syncthreads();
  }

  // ---- GEMM2: o = relu(t @ w2 + b2)
  f32x4 a2[4][2];
#pragma unroll
  for (int rt = 0; rt < 4; ++rt)
#pragma unroll
    for (int ct = 0; ct < 2; ++ct) a2[rt][ct] = (f32x4){0.f, 0.f, 0.f, 0.f};
#pragma unroll
  for (int k0 = 0; k0 < CH; k0 += 32) {
    int kb = k0 + (g << 3);
    short8 af[4], bfr[2];
#pragma unroll
    for (int rt = 0; rt < 4; ++rt)
      af[rt] = *(const short8*)&zt[ZIDX((rt << 4) + lr, kb)];
#pragma unroll
    for (int ct = 0; ct < 2; ++ct)
      bfr[ct] = *(const short8*)&wt[ZIDX(cb + (ct << 4) + lr, kb)];
#pragma unroll
    for (int rt = 0; rt < 4; ++rt)
#pragma unroll
      for (int ct = 0; ct < 2; ++ct)
        a2[rt][ct] = __builtin_amdgcn_mfma_f32_16x16x32_bf16(
            af[rt], bfr[ct], a2[rt][ct], 0, 0, 0);
  }
  __syncthreads();

  // write output tile into zt (swizzled), then coalesced copy-out
#pragma unroll
  for (int rt = 0; rt < 4; ++rt)
#pragma unroll
    for (int ct = 0; ct < 2; ++ct) {
      int col = cb + (ct << 4) + lr;
      float bias = b2v[col];
#pragma unroll
      for (int r = 0; r < 4; ++r) {
        int row = (rt << 4) + (g << 2) + r;
        zt[ZIDX(row, col)] = f2b(fmaxf(a2[rt][ct][r] + bias, 0.f));
      }
    }
  __syncthreads();

  for (int i = tid; i < 1024; i += 256) {
    int mm = i >> 4, c0 = (i & 15) << 3;
    if (mm < nm) {
      uint4 v = *(const uint4*)&zt[ZIDX(mm, c0)];
      *(uint4*)&hout[(((size_t)(b * NN + t0 + mm)) << 7) + c0] = v;
    }
  }
}

// ---------------------------------------------------------------------------
// Heads (emb is bf16)
// ---------------------------------------------------------------------------
__global__ __launch_bounds__(256)
void heads_kernel(const u16* __restrict__ emb, const int* __restrict__ didx,
                  const int* __restrict__ nopp, const float* __restrict__ pol_w,
                  const float* __restrict__ pol_b, const float* __restrict__ val_w,
                  const float* __restrict__ val_b, float* __restrict__ out) {
  int gw = (blockIdx.x * blockDim.x + threadIdx.x) >> 6;
  int lane = threadIdx.x & 63;
  if (gw >= BB * KK) return;
  int b = gw / KK, k = gw - b * KK;
  int node = didx[b * KK + k];
  const u16* e = emb + (((size_t)(b * NN + node)) << 7);
  u32 v = *(const u32*)&e[lane << 1];
  float f0 = __uint_as_float(v << 16);
  float f1 = __uint_as_float(v & 0xffff0000u);
  float s = f0 * pol_w[lane << 1] + f1 * pol_w[(lane << 1) + 1];
#pragma unroll
  for (int off = 32; off; off >>= 1) s += __shfl_down(s, off);
  if (lane == 0) out[b * KK + k] = s + pol_b[0];
  if (k == nopp[0]) {
    float vv = f0 * val_w[lane << 1] + f1 * val_w[(lane << 1) + 1];
#pragma unroll
    for (int off = 32; off; off >>= 1) vv += __shfl_down(vv, off);
    if (lane == 0) out[BB * KK + b] = vv + val_b[0];
  }
}

// ---------------------------------------------------------------------------
extern "C" void kernel_launch(void* const* d_in, const int* in_sizes, int n_in,
                              void* d_out, int out_size, void* d_ws, size_t ws_size,
                              hipStream_t stream) {
  const float* x     = (const float*)d_in[0];
  const int*   edges = (const int*)d_in[1];
  const int*   didx  = (const int*)d_in[2];
  const int*   nopp  = (const int*)d_in[3];
  const float* w1f   = (const float*)d_in[4];
  const float* w1r   = (const float*)d_in[5];
  const float* w2    = (const float*)d_in[6];
  const float* b1    = (const float*)d_in[7];
  const float* b2    = (const float*)d_in[8];
  const float* pol_w = (const float*)d_in[9];
  const float* pol_b = (const float*)d_in[10];
  const float* val_w = (const float*)d_in[11];
  const float* val_b = (const float*)d_in[12];
  float* out = (float*)d_out;

  char* ws = (char*)d_ws;
  u16* hA = (u16*)ws;            ws += (size_t)BB * NN * CH * 2;   // 51.2 MB
  u16* hB = (u16*)ws;            ws += (size_t)BB * NN * CH * 2;   // 51.2 MB
  u16* img = (u16*)ws;           ws += (size_t)5 * CH * CH * 2;    // 160 KB
  int* offs = (int*)ws;          ws += (size_t)BB * (NN + 1) * 4;
  int* woff = (int*)ws;          ws += (size_t)BB * NN * 4;
  int* cnt  = (int*)ws;          ws += (size_t)BB * NN * 4;
  int* csr  = (int*)ws;          ws += (size_t)BB * EE * 4;

  hipMemsetAsync(cnt, 0, (size_t)BB * NN * 4, stream);
  prep_weights<<<(5 * CH * CH + 255) / 256, 256, 0, stream>>>(w1r, w2, img);
  csr_count<<<1250, 256, 0, stream>>>(edges, cnt);
  csr_scan<<<BB, 256, 0, stream>>>(cnt, offs, woff);
  csr_fill<<<1250, 256, 0, stream>>>(edges, woff, csr);

  const int tiles = BB * NTILES;
  gin_layer<true><<<tiles, 256, 0, stream>>>(
      x, hA, offs, csr, w1f, nullptr, img, b1, b2);
  gin_layer<false><<<tiles, 256, 0, stream>>>(
      hA, hB, offs, csr, nullptr, img + 1 * 16384, img + 2 * 16384,
      b1 + CH, b2 + CH);
  gin_layer<false><<<tiles, 256, 0, stream>>>(
      hB, hA, offs, csr, nullptr, img + 3 * 16384, img + 4 * 16384,
      b1 + 2 * CH, b2 + 2 * CH);

  heads_kernel<<<(BB * KK * 64 + 255) / 256, 256, 0, stream>>>(
      hA, didx, nopp, pol_w, pol_b, val_w, val_b, out);
}

// Round 3
// 331.848 us; speedup vs baseline: 4.4157x; 1.3322x over previous
//
#include <hip/hip_runtime.h>
#include <hip/hip_bf16.h>

#define BB 4
#define NN 50000
#define EE 160000
#define KK 1000
#define CH 128
#define TM 64
#define NTILES ((NN + TM - 1) / TM)   // 782
#define SCAN_CHUNK 2048
#define SCAN_NB ((NN + SCAN_CHUNK - 1) / SCAN_CHUNK)  // 25

typedef unsigned short u16;
typedef unsigned int u32;
typedef __attribute__((ext_vector_type(8))) short short8;
typedef __attribute__((ext_vector_type(4))) float f32x4;

// swizzled index into a [rows][128] u16 LDS tile: XOR bits 3..5 of k with row&7
// (byte_off ^= (row&7)<<4) -> conflict-free ds_read_b128 fragment loads (G4)
__device__ __forceinline__ int ZIDX(int m, int k) {
  return (m << 7) | (k ^ ((m & 7) << 3));
}

__device__ __forceinline__ u16 f2b(float f) {
  __hip_bfloat16 h = __float2bfloat16(f);   // RNE
  return *reinterpret_cast<u16*>(&h);
}
__device__ __forceinline__ float b2f(u32 lo16) {
  return __uint_as_float(lo16 << 16);
}

// ---------------------------------------------------------------------------
// CSR build
// ---------------------------------------------------------------------------
__global__ __launch_bounds__(256)
void csr_count(const int* __restrict__ edges, int* __restrict__ cnt) {
  int stride = gridDim.x * blockDim.x;
  for (int i = blockIdx.x * blockDim.x + threadIdx.x; i < BB * EE; i += stride) {
    int b = i / EE, e = i - b * EE;
    int dst = edges[(b * 2 + 1) * EE + e];
    atomicAdd(&cnt[b * NN + dst], 1);
  }
}

// parallel scan, pass 1: per-block local exclusive scan (2048 elems/block)
__global__ __launch_bounds__(256)
void scan_local(const int* __restrict__ cnt, int* __restrict__ offs,
                int* __restrict__ bsum) {
  __shared__ int sdata[256];
  const int g = blockIdx.y, blk = blockIdx.x, t = threadIdx.x;
  const int i0 = blk * SCAN_CHUNK + t * 8;
  int v[8];
  int s = 0;
#pragma unroll
  for (int j = 0; j < 8; ++j) {
    int i = i0 + j;
    v[j] = (i < NN) ? cnt[g * NN + i] : 0;
    s += v[j];
  }
  sdata[t] = s;
  __syncthreads();
#pragma unroll
  for (int off = 1; off < 256; off <<= 1) {
    int vv = (t >= off) ? sdata[t - off] : 0;
    __syncthreads();
    sdata[t] += vv;
    __syncthreads();
  }
  int run = sdata[t] - s;  // exclusive prefix of this thread's chunk
#pragma unroll
  for (int j = 0; j < 8; ++j) {
    int i = i0 + j;
    if (i < NN) offs[g * (NN + 1) + i] = run;
    run += v[j];
  }
  if (t == 255) bsum[g * SCAN_NB + blk] = sdata[255];
}

// parallel scan, pass 2: add block offsets; emit offs (final) and woff copy
__global__ __launch_bounds__(256)
void scan_add(int* __restrict__ offs, int* __restrict__ woff,
              const int* __restrict__ bsum) {
  const int g = blockIdx.y, blk = blockIdx.x, t = threadIdx.x;
  int boff = 0;
  for (int j = 0; j < blk; ++j) boff += bsum[g * SCAN_NB + j];
  const int i0 = blk * SCAN_CHUNK + t * 8;
#pragma unroll
  for (int j = 0; j < 8; ++j) {
    int i = i0 + j;
    if (i < NN) {
      int val = offs[g * (NN + 1) + i] + boff;
      offs[g * (NN + 1) + i] = val;
      woff[g * NN + i] = val;
    }
  }
  if (blk == SCAN_NB - 1 && t == 255)
    offs[g * (NN + 1) + NN] = boff + bsum[g * SCAN_NB + blk];
}

__global__ __launch_bounds__(256)
void csr_fill(const int* __restrict__ edges, int* __restrict__ woff,
              int* __restrict__ csr_src) {
  int stride = gridDim.x * blockDim.x;
  for (int i = blockIdx.x * blockDim.x + threadIdx.x; i < BB * EE; i += stride) {
    int b = i / EE, e = i - b * EE;
    int src = edges[(b * 2) * EE + e];
    int dst = edges[(b * 2 + 1) * EE + e];
    int pos = atomicAdd(&woff[b * NN + dst], 1);
    csr_src[b * EE + pos] = src;
  }
}

// ---------------------------------------------------------------------------
// Weight prep: bf16, transposed (n-major), pre-swizzled LDS images.
// mats: 0:w2[0]  1:w1r[0]  2:w2[1]  3:w1r[1]  4:w2[2]
// ---------------------------------------------------------------------------
__global__ __launch_bounds__(256)
void prep_weights(const float* __restrict__ w1r, const float* __restrict__ w2,
                  u16* __restrict__ img) {
  int i = blockIdx.x * blockDim.x + threadIdx.x;
  if (i >= 5 * CH * CH) return;
  int mat = i >> 14, rem = i & 16383;
  int k = rem >> 7, n = rem & 127;
  const float* src;
  switch (mat) {
    case 0: src = w2; break;
    case 1: src = w1r; break;
    case 2: src = w2 + 16384; break;
    case 3: src = w1r + 16384; break;
    default: src = w2 + 32768; break;
  }
  img[(mat << 14) + ZIDX(n, k)] = f2b(src[(k << 7) + n]);
}

// ---------------------------------------------------------------------------
// Fused GIN layer: gather (CSR) + dual MFMA GEMM + relu, bf16 h in/out.
// Tile 64 nodes x 128 ch, 256 threads (4 waves). Wave w owns 32 out-cols.
// LDS: zt[64][128] bf16 (swz) + wt[128][128] bf16 (swz) = 48KB -> 3 blk/CU.
// ---------------------------------------------------------------------------
template <bool L0>
__global__ __launch_bounds__(256)
void gin_layer(const void* __restrict__ hin_v, u16* __restrict__ hout,
               const int* __restrict__ offs, const int* __restrict__ csr_src,
               const float* __restrict__ w1f,       // L0 only (128)
               const u16* __restrict__ img_w1,      // !L0
               const u16* __restrict__ img_w2,
               const float* __restrict__ b1v, const float* __restrict__ b2v) {
  __shared__ u16 zt[TM * CH];
  __shared__ u16 wt[CH * CH];
  __shared__ float part[L0 ? TM * 4 : 1];

  const int tid = threadIdx.x;
  const int lane = tid & 63;
  const int wv = tid >> 6;
  const int g = lane >> 4;    // k-group within frag
  const int lr = lane & 15;   // A-row / B-col within subtile
  const int cb = wv * 32;

  const int tile = blockIdx.x;
  const int b = tile / NTILES;
  const int t0 = (tile - b * NTILES) * TM;
  const int nm = min(TM, NN - t0);

  // stage first weight (w1 for !L0, w2 for L0) — images are pre-swizzled
  {
    const uint4* src = (const uint4*)(L0 ? img_w2 : img_w1);
    uint4* dst = (uint4*)wt;
    for (int i = tid; i < 2048; i += 256) dst[i] = src[i];
  }

  // ---- stage A-tile: z = h[dst] + sum_{src} h[src]  (4 threads/row, 32ch ea)
  const int m = tid >> 2;
  const int p = tid & 3;
  const int gnode = t0 + m;
  int start = 0, end = 0;
  if (m < nm) {
    start = offs[b * (NN + 1) + gnode];
    end = offs[b * (NN + 1) + gnode + 1];
  }

  if (L0) {
    const float* x = (const float*)hin_v;
    float s = 0.f;
    if (m < nm) {
      if (p == 0) s = x[b * NN + gnode];
      for (int e = start + p; e < end; e += 4) s += x[b * NN + csr_src[b * EE + e]];
    }
    part[(m << 2) + p] = s;
    __syncthreads();
    float z0 = part[m << 2] + part[(m << 2) + 1] + part[(m << 2) + 2] +
               part[(m << 2) + 3];
    for (int j = 0; j < 4; ++j) {
      int c0 = (p << 5) + (j << 3);
      short8 tv;
#pragma unroll
      for (int t = 0; t < 8; ++t)
        tv[t] = (short)f2b(fmaxf(z0 * w1f[c0 + t] + b1v[c0 + t], 0.f));
      *(short8*)&zt[ZIDX(m, c0)] = tv;
    }
    __syncthreads();
  } else {
    const u16* h = (const u16*)hin_v;
    float acc[32];
#pragma unroll
    for (int t = 0; t < 32; ++t) acc[t] = 0.f;
    if (m < nm) {
      {  // self
        const uint4* hr = (const uint4*)(h + ((size_t)(b * NN + gnode) << 7));
#pragma unroll
        for (int j = 0; j < 4; ++j) {
          uint4 v = hr[(p << 2) + j];
          acc[j*8+0] += b2f(v.x & 0xffff); acc[j*8+1] += b2f(v.x >> 16);
          acc[j*8+2] += b2f(v.y & 0xffff); acc[j*8+3] += b2f(v.y >> 16);
          acc[j*8+4] += b2f(v.z & 0xffff); acc[j*8+5] += b2f(v.z >> 16);
          acc[j*8+6] += b2f(v.w & 0xffff); acc[j*8+7] += b2f(v.w >> 16);
        }
      }
      for (int e = start; e < end; ++e) {
        int src = csr_src[b * EE + e];
        const uint4* hr = (const uint4*)(h + ((size_t)(b * NN + src) << 7));
#pragma unroll
        for (int j = 0; j < 4; ++j) {
          uint4 v = hr[(p << 2) + j];
          acc[j*8+0] += b2f(v.x & 0xffff); acc[j*8+1] += b2f(v.x >> 16);
          acc[j*8+2] += b2f(v.y & 0xffff); acc[j*8+3] += b2f(v.y >> 16);
          acc[j*8+4] += b2f(v.z & 0xffff); acc[j*8+5] += b2f(v.z >> 16);
          acc[j*8+6] += b2f(v.w & 0xffff); acc[j*8+7] += b2f(v.w >> 16);
        }
      }
    }
    for (int j = 0; j < 4; ++j) {
      int c0 = (p << 5) + (j << 3);
      short8 tv;
#pragma unroll
      for (int t = 0; t < 8; ++t) tv[t] = (short)f2b(acc[(j << 3) + t]);
      *(short8*)&zt[ZIDX(m, c0)] = tv;
    }
    __syncthreads();

    // ---- GEMM1: t = relu(z @ w1 + b1)
    f32x4 a1[4][2];
#pragma unroll
    for (int rt = 0; rt < 4; ++rt)
#pragma unroll
      for (int ct = 0; ct < 2; ++ct) a1[rt][ct] = (f32x4){0.f, 0.f, 0.f, 0.f};
#pragma unroll
    for (int k0 = 0; k0 < CH; k0 += 32) {
      int kb = k0 + (g << 3);
      short8 af[4], bfr[2];
#pragma unroll
      for (int rt = 0; rt < 4; ++rt)
        af[rt] = *(const short8*)&zt[ZIDX((rt << 4) + lr, kb)];
#pragma unroll
      for (int ct = 0; ct < 2; ++ct)
        bfr[ct] = *(const short8*)&wt[ZIDX(cb + (ct << 4) + lr, kb)];
#pragma unroll
      for (int rt = 0; rt < 4; ++rt)
#pragma unroll
        for (int ct = 0; ct < 2; ++ct)
          a1[rt][ct] = __builtin_amdgcn_mfma_f32_16x16x32_bf16(
              af[rt], bfr[ct], a1[rt][ct], 0, 0, 0);
    }
    __syncthreads();  // all zt/wt reads done

    // write t into zt (swizzled); stage w2 into wt
    {
      const uint4* src = (const uint4*)img_w2;
      uint4* dst = (uint4*)wt;
      for (int i = tid; i < 2048; i += 256) dst[i] = src[i];
    }
#pragma unroll
    for (int rt = 0; rt < 4; ++rt)
#pragma unroll
      for (int ct = 0; ct < 2; ++ct) {
        int col = cb + (ct << 4) + lr;
        float bias = b1v[col];
#pragma unroll
        for (int r = 0; r < 4; ++r) {
          int row = (rt << 4) + (g << 2) + r;
          zt[ZIDX(row, col)] = f2b(fmaxf(a1[rt][ct][r] + bias, 0.f));
        }
      }
    __syncthreads();
  }

  // ---- GEMM2: o = relu(t @ w2 + b2)
  f32x4 a2[4][2];
#pragma unroll
  for (int rt = 0; rt < 4; ++rt)
#pragma unroll
    for (int ct = 0; ct < 2; ++ct) a2[rt][ct] = (f32x4){0.f, 0.f, 0.f, 0.f};
#pragma unroll
  for (int k0 = 0; k0 < CH; k0 += 32) {
    int kb = k0 + (g << 3);
    short8 af[4], bfr[2];
#pragma unroll
    for (int rt = 0; rt < 4; ++rt)
      af[rt] = *(const short8*)&zt[ZIDX((rt << 4) + lr, kb)];
#pragma unroll
    for (int ct = 0; ct < 2; ++ct)
      bfr[ct] = *(const short8*)&wt[ZIDX(cb + (ct << 4) + lr, kb)];
#pragma unroll
    for (int rt = 0; rt < 4; ++rt)
#pragma unroll
      for (int ct = 0; ct < 2; ++ct)
        a2[rt][ct] = __builtin_amdgcn_mfma_f32_16x16x32_bf16(
            af[rt], bfr[ct], a2[rt][ct], 0, 0, 0);
  }
  __syncthreads();

  // write output tile into zt (swizzled), then coalesced copy-out
#pragma unroll
  for (int rt = 0; rt < 4; ++rt)
#pragma unroll
    for (int ct = 0; ct < 2; ++ct) {
      int col = cb + (ct << 4) + lr;
      float bias = b2v[col];
#pragma unroll
      for (int r = 0; r < 4; ++r) {
        int row = (rt << 4) + (g << 2) + r;
        zt[ZIDX(row, col)] = f2b(fmaxf(a2[rt][ct][r] + bias, 0.f));
      }
    }
  __syncthreads();

  for (int i = tid; i < 1024; i += 256) {
    int mm = i >> 4, c0 = (i & 15) << 3;
    if (mm < nm) {
      uint4 v = *(const uint4*)&zt[ZIDX(mm, c0)];
      *(uint4*)&hout[(((size_t)(b * NN + t0 + mm)) << 7) + c0] = v;
    }
  }
}

// ---------------------------------------------------------------------------
// Heads (emb is bf16)
// ---------------------------------------------------------------------------
__global__ __launch_bounds__(256)
void heads_kernel(const u16* __restrict__ emb, const int* __restrict__ didx,
                  const int* __restrict__ nopp, const float* __restrict__ pol_w,
                  const float* __restrict__ pol_b, const float* __restrict__ val_w,
                  const float* __restrict__ val_b, float* __restrict__ out) {
  int gw = (blockIdx.x * blockDim.x + threadIdx.x) >> 6;
  int lane = threadIdx.x & 63;
  if (gw >= BB * KK) return;
  int b = gw / KK, k = gw - b * KK;
  int node = didx[b * KK + k];
  const u16* e = emb + (((size_t)(b * NN + node)) << 7);
  u32 v = *(const u32*)&e[lane << 1];
  float f0 = __uint_as_float(v << 16);
  float f1 = __uint_as_float(v & 0xffff0000u);
  float s = f0 * pol_w[lane << 1] + f1 * pol_w[(lane << 1) + 1];
#pragma unroll
  for (int off = 32; off; off >>= 1) s += __shfl_down(s, off);
  if (lane == 0) out[b * KK + k] = s + pol_b[0];
  if (k == nopp[0]) {
    float vv = f0 * val_w[lane << 1] + f1 * val_w[(lane << 1) + 1];
#pragma unroll
    for (int off = 32; off; off >>= 1) vv += __shfl_down(vv, off);
    if (lane == 0) out[BB * KK + b] = vv + val_b[0];
  }
}

// ---------------------------------------------------------------------------
extern "C" void kernel_launch(void* const* d_in, const int* in_sizes, int n_in,
                              void* d_out, int out_size, void* d_ws, size_t ws_size,
                              hipStream_t stream) {
  const float* x     = (const float*)d_in[0];
  const int*   edges = (const int*)d_in[1];
  const int*   didx  = (const int*)d_in[2];
  const int*   nopp  = (const int*)d_in[3];
  const float* w1f   = (const float*)d_in[4];
  const float* w1r   = (const float*)d_in[5];
  const float* w2    = (const float*)d_in[6];
  const float* b1    = (const float*)d_in[7];
  const float* b2    = (const float*)d_in[8];
  const float* pol_w = (const float*)d_in[9];
  const float* pol_b = (const float*)d_in[10];
  const float* val_w = (const float*)d_in[11];
  const float* val_b = (const float*)d_in[12];
  float* out = (float*)d_out;

  char* ws = (char*)d_ws;
  u16* hA = (u16*)ws;            ws += (size_t)BB * NN * CH * 2;   // 51.2 MB
  u16* hB = (u16*)ws;            ws += (size_t)BB * NN * CH * 2;   // 51.2 MB
  u16* img = (u16*)ws;           ws += (size_t)5 * CH * CH * 2;    // 160 KB
  int* offs = (int*)ws;          ws += (size_t)BB * (NN + 1) * 4;
  int* woff = (int*)ws;          ws += (size_t)BB * NN * 4;
  int* cnt  = (int*)ws;          ws += (size_t)BB * NN * 4;
  int* bsum = (int*)ws;          ws += (size_t)BB * SCAN_NB * 4;
  int* csr  = (int*)ws;          ws += (size_t)BB * EE * 4;

  hipMemsetAsync(cnt, 0, (size_t)BB * NN * 4, stream);
  prep_weights<<<(5 * CH * CH + 255) / 256, 256, 0, stream>>>(w1r, w2, img);
  csr_count<<<1250, 256, 0, stream>>>(edges, cnt);
  scan_local<<<dim3(SCAN_NB, BB), 256, 0, stream>>>(cnt, offs, bsum);
  scan_add<<<dim3(SCAN_NB, BB), 256, 0, stream>>>(offs, woff, bsum);
  csr_fill<<<1250, 256, 0, stream>>>(edges, woff, csr);

  const int tiles = BB * NTILES;
  gin_layer<true><<<tiles, 256, 0, stream>>>(
      x, hA, offs, csr, w1f, nullptr, img, b1, b2);
  gin_layer<false><<<tiles, 256, 0, stream>>>(
      hA, hB, offs, csr, nullptr, img + 1 * 16384, img + 2 * 16384,
      b1 + CH, b2 + CH);
  gin_layer<false><<<tiles, 256, 0, stream>>>(
      hB, hA, offs, csr, nullptr, img + 3 * 16384, img + 4 * 16384,
      b1 + 2 * CH, b2 + 2 * CH);

  heads_kernel<<<(BB * KK * 64 + 255) / 256, 256, 0, stream>>>(
      hA, didx, nopp, pol_w, pol_b, val_w, val_b, out);
}